// Round 4
// baseline (870.457 us; speedup 1.0000x reference)
//
#include <hip/hip_runtime.h>
#include <math.h>

#define V_ 128000
#define D_ 128
#define N_ 4
#define K_ 4
#define T_ 16
#define S_ 5
#define EPSF 1e-10f

// ws layout (float offsets)
#define WS_G      0          // [16][32][128][4] = 262144
#define WS_BEPS   262144     // [T][K][S][N][128] = 655360
#define WS_BX     917504     // [T][K][N][128] = 32768
#define WS_EQ2    950272     // [2][16][128] fp32 double-buffered = 4096
#define WS_EQBALL 954368     // [T][4][64][8] ushort = 16384 floats
#define WS_GRAM   970752     // [T][16][16] = 4096
#define WS_MM     974848     // [K][128] = 512
#define WS_BMM    975360     // [16][128] = 2048
#define WS_INTER  977408     // [K][16] = 64
#define WS_WK     977472     // [T][16] = 256
#define WS_SRHO   977728     // [T] = 16
#define WS_LNZ    977744     // [T] = 16
#define WS_ZPART  977760     // [T][2000] float = 32000
#define WS_HPART  1009760    // [T][125] float = 2000

typedef __attribute__((ext_vector_type(8))) short short8v;
typedef __attribute__((ext_vector_type(4))) float float4v;

__device__ __forceinline__ short bfb(float x) {
    unsigned u = __float_as_uint(x);
    u += 0x7fffu + ((u >> 16) & 1u);
    return (short)(u >> 16);
}

// Jacobi round-robin pairing, closed form. Round r in [0,15): pairs {15, r%15},
// {(r+s)%15, (r-s)%15} s=1..7. Returns partner and whether x is the p-side.
__device__ __forceinline__ void jpair(int x, int r, int& ox, bool& isp) {
    if (x == 15) { ox = r % 15; isp = true; return; }
    int s = x - r; s %= 15; if (s < 0) s += 15;
    if (s == 0) { ox = 15; isp = false; return; }
    int o = 2 * r - x; o %= 15; if (o < 0) o += 15;
    ox = o;
    isp = (s <= 7);
}

__device__ __forceinline__ void rotparams(float app, float aqq, float apq, float& c, float& s) {
    c = 1.f; s = 0.f;
    if (fabsf(apq) > 1e-20f) {
        float tau = (aqq - app) / (2.f * apq);
        float sq1 = sqrtf(1.f + tau * tau);
        float tt = (tau >= 0.f) ? 1.f / (tau + sq1) : 1.f / (tau - sq1);
        c = 1.f / sqrtf(1.f + tt * tt);
        s = tt * c;
    }
}

// ---------------- init: blocks 0-63 = G/Bx/beps prep; block 64 = state init ----------------
__global__ __launch_bounds__(256)
void i2_prep(const float* __restrict__ bases, const float* __restrict__ E,
             const float* __restrict__ noise, const int* __restrict__ tokens,
             const float* __restrict__ tension, const float* __restrict__ temperature,
             float* __restrict__ ws)
{
    int tid = threadIdx.x;
    if (blockIdx.x == 64) {
        for (int i = tid; i < 2560; i += 256) ws[WS_MM + i] = 0.0f;   // mm + bmm
        if (tid < 4) {
            int k = tid;
            float temp = fmaxf(fabsf(temperature[k]), 0.01f);
            for (int i = 0; i < 4; ++i) {
                float v[4]; float mx = -1e30f;
                for (int j = 0; j < 4; ++j) { v[j] = -tension[k*16 + i*4 + j] / temp; mx = fmaxf(mx, v[j]); }
                float se = 0.f;
                for (int j = 0; j < 4; ++j) { v[j] = expf(v[j] - mx); se += v[j]; }
                for (int j = 0; j < 4; ++j) ws[WS_INTER + k*16 + i*4 + j] = (i == j) ? 0.0f : v[j] / se;
            }
        }
        return;
    }
    int kn = blockIdx.x >> 2, q = blockIdx.x & 3;
    int k = kn >> 2, n = kn & 3;
    __shared__ __align__(16) float Blds[128 * 132];
    const float4* B4 = (const float4*)(bases + (size_t)kn * 16384);
    for (int idx = tid; idx < 4096; idx += 256) {
        int jrow = idx >> 5, c = idx & 31;
        float4 v = B4[jrow * 32 + c];
        *((float4*)&Blds[jrow * 132 + c * 4]) = v;
    }
    __syncthreads();
    int j1 = q * 32 + (tid >> 3);
    int l = tid & 7;
    float accg[16];
#pragma unroll
    for (int i = 0; i < 16; ++i) accg[i] = 0.f;
    for (int c = 0; c < 32; ++c) {
        float4 b1 = *((const float4*)&Blds[j1 * 132 + c * 4]);
#pragma unroll
        for (int i = 0; i < 16; ++i) {
            float4 b2 = *((const float4*)&Blds[(l + 8 * i) * 132 + c * 4]);
            accg[i] += b1.x * b2.x + b1.y * b2.y + b1.z * b2.z + b1.w * b2.w;
        }
    }
#pragma unroll
    for (int i = 0; i < 16; ++i) {
        int j2 = l + 8 * i;
        ws[WS_G + (((size_t)kn * 32 + (j2 >> 2)) * 128 + j1) * 4 + (j2 & 3)] = accg[i];
    }
    __shared__ __align__(16) float vecl[128];
    __shared__ float vred[2][128];
    int jv = tid & 127, ch = tid >> 7;
    for (int vi = q * 24; vi < q * 24 + 24; ++vi) {
        const float* src; int dstoff;
        if (vi < 16) {
            int tt = vi;
            src = E + (size_t)tokens[tt] * 128;
            dstoff = WS_BX + (tt * 4 + k) * 512 + n * 128;
        } else {
            int r2 = vi - 16; int tt = r2 / 5, s2 = r2 % 5;
            size_t off = (size_t)(((tt * 4 + k) * 5 + s2) * 4 + n) * 128;
            src = noise + off;
            dstoff = WS_BEPS + (int)off;
        }
        if (tid < 32) ((float4*)vecl)[tid] = ((const float4*)src)[tid];
        __syncthreads();
        float a2 = 0.f;
        for (int c = ch * 16; c < ch * 16 + 16; ++c) {
            float4 bv = *((const float4*)&Blds[jv * 132 + c * 4]);
            float4 xv = ((const float4*)vecl)[c];
            a2 += bv.x * xv.x + bv.y * xv.y + bv.z * xv.z + bv.w * xv.w;
        }
        vred[ch][jv] = a2;
        __syncthreads();
        if (tid < 128) ws[dstoff + tid] = vred[0][tid] + vred[1][tid];
        __syncthreads();
    }
}

// ---------------- KAP: 4 blocks; everything sequential for one token ----------------
__global__ __launch_bounds__(512, 2)
void kap(const float* __restrict__ E, const float* __restrict__ noise,
         const int* __restrict__ tokens, const float* __restrict__ bases,
         const float* __restrict__ target_sim, const float* __restrict__ step_size,
         const float* __restrict__ gate_logit, const float* __restrict__ decay_base,
         const float* __restrict__ sensitivity,
         float* __restrict__ ws, int t)
{
    const int k = blockIdx.x;
    const int tid = threadIdx.x;
    const int n = tid >> 7, j = tid & 127;
    const int kn = k * 4 + n;
    const int wave = tid >> 6;
    const int ebuf = t & 1;

    float g[128];
    const float4* G4 = (const float4*)(ws + WS_G);
#pragma unroll
    for (int c = 0; c < 32; ++c) {
        float4 v = G4[((size_t)kn * 32 + c) * 128 + j];
        g[4*c+0] = v.x; g[4*c+1] = v.y; g[4*c+2] = v.z; g[4*c+3] = v.w;
    }

    // Gram of token t-1 (reads other buffer; independent of everything below)
    if (t > 0) {
        const float* eqR = ws + WS_EQ2 + (ebuf ^ 1) * 2048;
        int r = tid >> 7, c = (tid >> 3) & 15, sub = tid & 7;
        const float4* ra = (const float4*)(eqR + (4 * k + r) * 128 + sub * 16);
        const float4* rb = (const float4*)(eqR + c * 128 + sub * 16);
        float dp = 0.f;
#pragma unroll
        for (int q = 0; q < 4; ++q) {
            float4 a = ra[q], b2 = rb[q];
            dp += a.x * b2.x + a.y * b2.y + a.z * b2.z + a.w * b2.w;
        }
        dp += __shfl_xor(dp, 1); dp += __shfl_xor(dp, 2); dp += __shfl_xor(dp, 4);
        if (sub == 0) ws[WS_GRAM + (t - 1) * 256 + (4 * k + r) * 16 + c] = dp;
    }

    __shared__ float xl[128], ml[128], mmL[128];
    __shared__ __align__(16) float uL[4][128], beL[4][128], aL[4][128], exL[4][128];
    __shared__ float interL[16];
    __shared__ float wred[8][8];
    __shared__ float Ptab[16], U2t[4], D1t[4], D2t[4];
    __shared__ float scal[1];

    int tok = tokens[t];
    if (tid < 16) interL[tid] = ws[WS_INTER + k * 16 + tid];
    if (n == 0) { xl[j] = E[(size_t)tok * 128 + j]; ml[j] = ws[WS_MM + k * 128 + j]; }
    __syncthreads();

    // novelty / decay
    float vx = 0.f, vm = 0.f, vd = 0.f;
    if (n == 0) { float xv = xl[j], mv = ml[j]; vx = xv * xv; vm = mv * mv; vd = xv * mv; }
    for (int m = 32; m; m >>= 1) { vx += __shfl_xor(vx, m); vm += __shfl_xor(vm, m); vd += __shfl_xor(vd, m); }
    if ((tid & 63) == 0) { wred[wave][0] = vx; wred[wave][1] = vm; wred[wave][2] = vd; }
    __syncthreads();
    if (tid == 0) {
        float sx = 0, sm = 0, sd = 0;
        for (int w = 0; w < 8; ++w) { sx += wred[w][0]; sm += wred[w][1]; sd += wred[w][2]; }
        float xnorm = sqrtf(sx) + EPSF, mnorm = sqrtf(sm) + EPSF;
        float nov = 1.0f - sd / (xnorm * mnorm);
        float novelty = (mnorm > 1e-8f) ? nov : 1.0f;
        scal[0] = 1.0f / (1.0f + expf(-(decay_base[0] - fabsf(sensitivity[0]) * novelty)));
    }
    __syncthreads();
    float dec = scal[0];
    float tgt = target_sim[k];
    float stp = fminf(fmaxf(fabsf(step_size[k]), 0.001f), 0.5f);
    float gate = 1.0f / (1.0f + expf(-gate_logit[k]));

    float e0v = ws[WS_BX + (t * 4 + k) * 512 + n * 128 + j] + dec * ws[WS_BMM + kn * 128 + j];
    exL[n][j] = e0v;
    aL[n][j] = 0.f;
    beL[n][j] = 0.f;
    uL[n][j] = xl[j] + dec * ml[j];
    __syncthreads();

    for (int s = 0; s < 5; ++s) {
        float pe = exL[n][j];
        float em[4];
#pragma unroll
        for (int m = 0; m < 4; ++m) em[m] = exL[m][j];
        float av = aL[n][j], bev = beL[n][j], uv = uL[n][j];
        float r[7];
#pragma unroll
        for (int m = 0; m < 4; ++m) r[m] = pe * em[m];
        r[4] = uv * uv;
        r[5] = (e0v + bev) * av;
        r[6] = av * (pe - e0v - bev);
#pragma unroll
        for (int m2 = 32; m2; m2 >>= 1) {
#pragma unroll
            for (int q = 0; q < 7; ++q) r[q] += __shfl_xor(r[q], m2);
        }
        if ((tid & 63) == 0) {
#pragma unroll
            for (int q = 0; q < 7; ++q) wred[wave][q] = r[q];
        }
        __syncthreads();
        if (tid < 16) { int nn = tid >> 2, m = tid & 3; Ptab[tid] = wred[2*nn][m] + wred[2*nn+1][m]; }
        else if (tid < 20) {
            int nn = tid - 16;
            U2t[nn] = wred[2*nn][4] + wred[2*nn+1][4];
            D1t[nn] = wred[2*nn][5] + wred[2*nn+1][5];
            D2t[nn] = wred[2*nn][6] + wred[2*nn+1][6];
        }
        __syncthreads();
        float ssum = 0.f;
#pragma unroll
        for (int m = 0; m < 4; ++m) ssum += sqrtf(fmaxf(U2t[m] + 2.f * D1t[m] + D2t[m], 0.f));
        float scale = 0.25f * ssum + EPSF;
        float cn = gate * scale * 0.01f;

        float Pnn = Ptab[n * 4 + n];
        float enn = sqrtf(fmaxf(Pnn, 0.f)) + EPSF;
        float fsh = 0.f;
#pragma unroll
        for (int m = 0; m < 4; ++m) {
            float Pmm = Ptab[m * 4 + m];
            float Pnm = Ptab[n * 4 + m];
            float enm = sqrtf(fmaxf(Pmm, 0.f)) + EPSF;
            float cosnm = Pnm / (enn * enm);
            float fm = (cosnm - tgt) * interL[n * 4 + m];
            float dnn = sqrtf(fmaxf(Pnn - 2.f * Pnm + Pmm, 0.f)) + EPSF;
            fsh += (fm / dnn) * (pe - em[m]);
        }
        int nzoff = (((t * 4 + k) * 5 + s) * 4 + n) * 128 + j;
        float anew = av + stp * fsh;
        float benew = bev + cn * ws[WS_BEPS + nzoff];
        uL[n][j] = uv + cn * noise[nzoff];
        aL[n][j] = anew;
        beL[n][j] = benew;
        __syncthreads();
        float y = 0.f;
        const float4* a4 = (const float4*)aL[n];
#pragma unroll
        for (int c = 0; c < 32; ++c) {
            float4 avv = a4[c];
            y += g[4*c+0] * avv.x + g[4*c+1] * avv.y + g[4*c+2] * avv.z + g[4*c+3] * avv.w;
        }
        exL[n][j] = e0v + y + benew;
        __syncthreads();
    }

    // eq finalize: eq[n][d] = u[n][d] + sum_j a[n][j] * B[kn][j][d]
    {
        int n2 = tid >> 7, d = tid & 127;
        int kn2 = k * 4 + n2;
        const float* Bp = bases + (size_t)kn2 * 16384;
        const float4* a4 = (const float4*)aL[n2];
        float accv = 0.f;
#pragma unroll 8
        for (int c = 0; c < 32; ++c) {
            float4 av = a4[c];
            accv += av.x * Bp[(4*c+0)*128 + d] + av.y * Bp[(4*c+1)*128 + d]
                  + av.z * Bp[(4*c+2)*128 + d] + av.w * Bp[(4*c+3)*128 + d];
        }
        float eqd = uL[n2][d] + accv;
        ws[WS_EQ2 + ebuf * 2048 + kn2 * 128 + d] = eqd;
        {
            int c2 = d >> 5, lg = (d >> 3) & 3, jj = d & 7;
            int lane8 = lg * 16 + kn2;
            ((unsigned short*)(ws + WS_EQBALL))[t * 2048 + (c2 * 64 + lane8) * 8 + jj] = (unsigned short)bfb(eqd);
        }
        __syncthreads();           // exL free after this point
        exL[n2][d] = eqd;          // reuse as eqL
        float sq = eqd * eqd;
        for (int m = 32; m; m >>= 1) sq += __shfl_xor(sq, m);
        if ((tid & 63) == 0) wred[tid >> 6][0] = sq;
        __syncthreads();
        // wk per k (same for the block's 4 kn entries)
        if (tid < 4) {
            float ssum4 = wred[0][0] + wred[1][0] + wred[2][0] + wred[3][0]
                        + wred[4][0] + wred[5][0] + wred[6][0] + wred[7][0];
            ws[WS_WK + t * 16 + 4 * k + tid] = 1.0f / (4.0f * (ssum4 + EPSF));
        }
        // mm update
        if (tid < 128) {
            float eqm = 0.25f * (exL[0][tid] + exL[1][tid] + exL[2][tid] + exL[3][tid]);
            float mmn = dec * ml[tid] + (1.f - dec) * eqm;
            ws[WS_MM + k * 128 + tid] = mmn;
            mmL[tid] = mmn;
        }
        __syncthreads();
        // bmm for next token: bmm[kn][j] = B[kn] row j . mm
        int jr = tid & 127, nb = tid >> 7;
        int knb = k * 4 + nb;
        const float4* Brow = (const float4*)(bases + (size_t)knb * 16384 + (size_t)jr * 128);
        const float4* mm4 = (const float4*)mmL;
        float acc = 0.f;
#pragma unroll 8
        for (int c = 0; c < 32; ++c) {
            float4 bv = Brow[c]; float4 mv = mm4[c];
            acc += bv.x * mv.x + bv.y * mv.y + bv.z * mv.z + bv.w * mv.w;
        }
        ws[WS_BMM + knb * 128 + jr] = acc;
    }
}

// ---------------- mega: logits GEMM for all 16 tokens, 2 passes of 8 ----------------
__global__ __launch_bounds__(256, 2)
void mega(const float* __restrict__ E, float* __restrict__ ws, float* __restrict__ out)
{
    int b = blockIdx.x, tid = threadIdx.x;
    int pass = (b >= 500) ? 1 : 0;
    int bb = b - pass * 500;
    int tok0 = pass * 8;
    int lane = tid & 63, wv = tid >> 6;
    const short8v* eqB = (const short8v*)(ws + WS_EQBALL);
    short8v bfr[8][4];
#pragma unroll
    for (int tk = 0; tk < 8; ++tk)
#pragma unroll
        for (int c2 = 0; c2 < 4; ++c2) bfr[tk][c2] = eqB[(tok0 + tk) * 256 + c2 * 64 + lane];
    float wk[8], zl[8];
#pragma unroll
    for (int tk = 0; tk < 8; ++tk) {
        wk[tk] = ws[WS_WK + (tok0 + tk) * 16 + (lane & 15)];
        zl[tk] = 0.f;
    }
    int tilebase = (bb * 4 + wv) * 64;
#pragma unroll
    for (int it = 0; it < 4; ++it) {
        int rowB = tilebase + it * 16;
        const float* Erow = E + (size_t)(rowB + (lane & 15)) * 128 + ((lane >> 4) * 8);
        float4v acc[8];
#pragma unroll
        for (int tk = 0; tk < 8; ++tk) acc[tk] = (float4v){0.f, 0.f, 0.f, 0.f};
#pragma unroll
        for (int c2 = 0; c2 < 4; ++c2) {
            float4 e0 = *((const float4*)(Erow + c2 * 32));
            float4 e1 = *((const float4*)(Erow + c2 * 32 + 4));
            short8v a;
            a[0] = bfb(e0.x); a[1] = bfb(e0.y); a[2] = bfb(e0.z); a[3] = bfb(e0.w);
            a[4] = bfb(e1.x); a[5] = bfb(e1.y); a[6] = bfb(e1.z); a[7] = bfb(e1.w);
#pragma unroll
            for (int tk = 0; tk < 8; ++tk)
                acc[tk] = __builtin_amdgcn_mfma_f32_16x16x32_bf16(a, bfr[tk][c2], acc[tk], 0, 0, 0);
        }
#pragma unroll
        for (int tk = 0; tk < 8; ++tk) {
            float l0 = wk[tk] * acc[tk][0] * acc[tk][0];
            float l1 = wk[tk] * acc[tk][1] * acc[tk][1];
            float l2 = wk[tk] * acc[tk][2] * acc[tk][2];
            float l3 = wk[tk] * acc[tk][3] * acc[tk][3];
#pragma unroll
            for (int m = 1; m <= 8; m <<= 1) {
                l0 += __shfl_xor(l0, m); l1 += __shfl_xor(l1, m);
                l2 += __shfl_xor(l2, m); l3 += __shfl_xor(l3, m);
            }
            if ((lane & 15) == 0) {
                float4 st; st.x = l0; st.y = l1; st.z = l2; st.w = l3;
                *((float4*)(out + (size_t)(tok0 + tk) * V_ + rowB + (lane >> 4) * 4)) = st;
                zl[tk] += __expf(l0) + __expf(l1) + __expf(l2) + __expf(l3);
            }
        }
    }
#pragma unroll
    for (int tk = 0; tk < 8; ++tk) {
        float z = zl[tk];
        z += __shfl_xor(z, 16); z += __shfl_xor(z, 32);
        if (lane == 0) ws[WS_ZPART + (tok0 + tk) * 2000 + bb * 4 + wv] = z;
    }
}

// ---------------- zk: Z reduce (blk 0-15) + Gram for t=15 (blk 16) ----------------
__global__ __launch_bounds__(256)
void zk(float* __restrict__ ws)
{
    int b = blockIdx.x, tid = threadIdx.x;
    if (b < 16) {
        double s = 0.0;
        for (int i = tid; i < 2000; i += 256) s += (double)ws[WS_ZPART + b * 2000 + i];
        for (int m = 32; m; m >>= 1) s += __shfl_xor(s, m);
        __shared__ double sr[4];
        if ((tid & 63) == 0) sr[tid >> 6] = s;
        __syncthreads();
        if (tid == 0) ws[WS_LNZ + b] = (float)log(sr[0] + sr[1] + sr[2] + sr[3]);
    } else {
        const float* eqR = ws + WS_EQ2 + 2048;   // buffer (15 & 1) == 1
        int aa = tid >> 4, bb = tid & 15;
        const float4* ra = (const float4*)(eqR + aa * 128);
        const float4* rb = (const float4*)(eqR + bb * 128);
        float dp = 0.f;
#pragma unroll 8
        for (int c = 0; c < 32; ++c) {
            float4 a = ra[c], b2 = rb[c];
            dp += a.x * b2.x + a.y * b2.y + a.z * b2.z + a.w * b2.w;
        }
        ws[WS_GRAM + 15 * 256 + tid] = dp;
    }
}

// ---------------- fin1: blk 0-15 single-wave Jacobi; blk 16+ probs (4 elems/thread) ----------------
__global__ __launch_bounds__(256)
void fin1(float* __restrict__ ws, float* __restrict__ out)
{
    int b = blockIdx.x, tid = threadIdx.x;
    if (b < 16) {
        if (tid >= 64) return;
        int tt = b;
        __shared__ float Am[16 * 20];
        int i0 = tid >> 2, j40 = (tid & 3) * 4;
        const float* G = ws + WS_GRAM + tt * 256;
        float wv4[4];
#pragma unroll
        for (int kk = 0; kk < 4; ++kk) {
            float ss = G[(4*kk+0)*17] + G[(4*kk+1)*17] + G[(4*kk+2)*17] + G[(4*kk+3)*17];
            wv4[kk] = 1.0f / (4.0f * (ss + EPSF));
        }
#pragma unroll
        for (int m = 0; m < 4; ++m) {
            int jj = j40 + m;
            Am[i0 * 20 + jj] = sqrtf(wv4[i0 >> 2] * wv4[jj >> 2]) * G[i0 * 16 + jj];
        }
        for (int sw = 0; sw < 6; ++sw) {
            for (int r = 0; r < 15; ++r) {
                int oi; bool ip; jpair(i0, r, oi, ip);
                int p = ip ? i0 : oi, q = ip ? oi : i0;
                float c, s;
                rotparams(Am[p * 20 + p], Am[q * 20 + q], Am[p * 20 + q], c, s);
                float ci = c, siS = ip ? -s : s;
                float nv[4];
#pragma unroll
                for (int m = 0; m < 4; ++m) {
                    int jj = j40 + m;
                    int oj; bool jp2; jpair(jj, r, oj, jp2);
                    int pj = jp2 ? jj : oj, qj = jp2 ? oj : jj;
                    float cj, sj;
                    rotparams(Am[pj * 20 + pj], Am[qj * 20 + qj], Am[pj * 20 + qj], cj, sj);
                    float sjS = jp2 ? -sj : sj;
                    float a00 = Am[i0 * 20 + jj], a01 = Am[i0 * 20 + oj];
                    float a10 = Am[oi * 20 + jj], a11 = Am[oi * 20 + oj];
                    nv[m] = ci * cj * a00 + ci * sjS * a01 + siS * cj * a10 + siS * sjS * a11;
                }
#pragma unroll
                for (int m = 0; m < 4; ++m) Am[i0 * 20 + j40 + m] = nv[m];
            }
        }
        if (tid == 0) {
            float tot = 112.0f * 1e-12f;
            float lc[16];
            for (int a2 = 0; a2 < 16; ++a2) { lc[a2] = fmaxf(Am[a2 * 20 + a2], 1e-12f); tot += lc[a2]; }
            float S = 0.f;
            for (int a2 = 0; a2 < 16; ++a2) { float pp = lc[a2] / tot; S -= pp * fmaxf(logf(pp), -100.f); }
            float p0 = 1e-12f / tot;
            S -= 112.f * p0 * fmaxf(logf(p0), -100.f);
            out[(size_t)T_ * V_ + tt] = S;
            ws[WS_SRHO + tt] = S;
        }
    } else {
        int b2 = b - 16;
        int tt = b2 / 125, blk = b2 - tt * 125;
        int v = blk * 1024 + tid * 4;
        float lnZ = ws[WS_LNZ + tt];
        float* po = out + (size_t)tt * V_ + v;
        float4 l4 = *((const float4*)po);
        float lp0 = l4.x - lnZ, lp1 = l4.y - lnZ, lp2 = l4.z - lnZ, lp3 = l4.w - lnZ;
        float p0 = __expf(lp0), p1 = __expf(lp1), p2 = __expf(lp2), p3 = __expf(lp3);
        float4 st; st.x = p0; st.y = p1; st.z = p2; st.w = p3;
        *((float4*)po) = st;
        float hp = p0 * fmaxf(lp0, -100.f) + p1 * fmaxf(lp1, -100.f)
                 + p2 * fmaxf(lp2, -100.f) + p3 * fmaxf(lp3, -100.f);
        for (int m = 32; m; m >>= 1) hp += __shfl_xor(hp, m);
        __shared__ float hr[4];
        if ((tid & 63) == 0) hr[tid >> 6] = hp;
        __syncthreads();
        if (tid == 0) ws[WS_HPART + tt * 125 + blk] = hr[0] + hr[1] + hr[2] + hr[3];
    }
}

// ---------------- f2: per-token H reduction ----------------
__global__ __launch_bounds__(128)
void f2_final(float* __restrict__ ws, float* __restrict__ out)
{
    int t = blockIdx.x, tid = threadIdx.x;
    float s = (tid < 125) ? ws[WS_HPART + t * 125 + tid] : 0.f;
    for (int m = 32; m; m >>= 1) s += __shfl_xor(s, m);
    __shared__ float sr[2];
    if ((tid & 63) == 0) sr[tid >> 6] = s;
    __syncthreads();
    if (tid == 0) {
        float H = -(sr[0] + sr[1]);
        float S = ws[WS_SRHO + t];
        out[(size_t)T_ * V_ + T_ + t] = H;
        out[(size_t)T_ * V_ + 2 * T_ + t] = H - S;
    }
}

extern "C" void kernel_launch(void* const* d_in, const int* in_sizes, int n_in,
                              void* d_out, int out_size, void* d_ws, size_t ws_size,
                              hipStream_t stream)
{
    (void)in_sizes; (void)n_in; (void)out_size; (void)ws_size;
    const float* E           = (const float*)d_in[0];
    const float* bases       = (const float*)d_in[1];
    const float* tension     = (const float*)d_in[2];
    const float* temperature = (const float*)d_in[3];
    const float* target_sim  = (const float*)d_in[4];
    const float* step_size   = (const float*)d_in[5];
    const float* gate_logit  = (const float*)d_in[6];
    const float* decay_base  = (const float*)d_in[7];
    const float* sensitivity = (const float*)d_in[8];
    const float* noise       = (const float*)d_in[9];
    const int*   tokens      = (const int*)d_in[10];
    float* out = (float*)d_out;
    float* ws  = (float*)d_ws;

    i2_prep<<<65, 256, 0, stream>>>(bases, E, noise, tokens, tension, temperature, ws);
    for (int t = 0; t < T_; ++t) {
        kap<<<4, 512, 0, stream>>>(E, noise, tokens, bases, target_sim, step_size,
                                   gate_logit, decay_base, sensitivity, ws, t);
    }
    mega<<<1000, 256, 0, stream>>>(E, ws, out);
    zk<<<17, 256, 0, stream>>>(ws);
    fin1<<<16 + T_ * 125, 256, 0, stream>>>(ws, out);
    f2_final<<<T_, 128, 0, stream>>>(ws, out);
}

// Round 5
// 814.375 us; speedup vs baseline: 1.0689x; 1.0689x over previous
//
#include <hip/hip_runtime.h>
#include <math.h>

#define V_ 128000
#define D_ 128
#define N_ 4
#define K_ 4
#define T_ 16
#define S_ 5
#define EPSF 1e-10f

// ws layout (float offsets)
#define WS_G      0          // [16][32][128][4] = 262144
#define WS_BEPS   262144     // [T][K][S][N][128] = 655360
#define WS_BX     917504     // [T][K][N][128] = 32768
#define WS_EQ2    950272     // [2][16][128] fp32 double-buffered = 4096
#define WS_EQBALL 954368     // [T][4][64][8] ushort = 16384 floats
#define WS_GRAM   970752     // [T][16][16] = 4096
#define WS_MM     974848     // [K][128] = 512
#define WS_BMM    975360     // [16][128] = 2048
#define WS_INTER  977408     // [K][16] = 64
#define WS_WK     977472     // [T][16] = 256
#define WS_SRHO   977728     // [T] = 16
#define WS_LNZ    977744     // [T] = 16
#define WS_ZPART  977760     // [T][2000] float = 32000
#define WS_HPART  1009760    // [T][125] float = 2000

typedef __attribute__((ext_vector_type(8))) short short8v;
typedef __attribute__((ext_vector_type(4))) float float4v;

__device__ __forceinline__ short bfb(float x) {
    unsigned u = __float_as_uint(x);
    u += 0x7fffu + ((u >> 16) & 1u);
    return (short)(u >> 16);
}

// Jacobi round-robin pairing, closed form, consistent with the 8-lane enumeration:
// lane 0: {15, r%15}; lane l=1..7: {(r+l)%15, (r-l)%15}
__device__ __forceinline__ void jpair(int x, int r, int& ox, bool& isp) {
    if (x == 15) { ox = r % 15; isp = true; return; }
    int s = x - r; s %= 15; if (s < 0) s += 15;
    if (s == 0) { ox = 15; isp = false; return; }
    int o = 2 * r - x; o %= 15; if (o < 0) o += 15;
    ox = o;
    isp = (s <= 7);
}

__device__ __forceinline__ void rotfast(float app, float aqq, float apq, float& c, float& s) {
    c = 1.f; s = 0.f;
    if (fabsf(apq) > 1e-20f) {
        float tau = (aqq - app) * 0.5f * __builtin_amdgcn_rcpf(apq);
        float sq1 = __builtin_amdgcn_sqrtf(1.f + tau * tau);
        float den = tau + ((tau >= 0.f) ? sq1 : -sq1);
        float tt = __builtin_amdgcn_rcpf(den);
        c = __builtin_amdgcn_rsqf(1.f + tt * tt);
        s = tt * c;
    }
}

// ---------------- init: blocks 0-63 = G/Bx/beps prep; block 64 = state init ----------------
__global__ __launch_bounds__(256)
void i2_prep(const float* __restrict__ bases, const float* __restrict__ E,
             const float* __restrict__ noise, const int* __restrict__ tokens,
             const float* __restrict__ tension, const float* __restrict__ temperature,
             float* __restrict__ ws)
{
    int tid = threadIdx.x;
    if (blockIdx.x == 64) {
        for (int i = tid; i < 2560; i += 256) ws[WS_MM + i] = 0.0f;   // mm + bmm
        if (tid < 4) {
            int k = tid;
            float temp = fmaxf(fabsf(temperature[k]), 0.01f);
            for (int i = 0; i < 4; ++i) {
                float v[4]; float mx = -1e30f;
                for (int j = 0; j < 4; ++j) { v[j] = -tension[k*16 + i*4 + j] / temp; mx = fmaxf(mx, v[j]); }
                float se = 0.f;
                for (int j = 0; j < 4; ++j) { v[j] = expf(v[j] - mx); se += v[j]; }
                for (int j = 0; j < 4; ++j) ws[WS_INTER + k*16 + i*4 + j] = (i == j) ? 0.0f : v[j] / se;
            }
        }
        return;
    }
    int kn = blockIdx.x >> 2, q = blockIdx.x & 3;
    int k = kn >> 2, n = kn & 3;
    __shared__ __align__(16) float Blds[128 * 132];
    const float4* B4 = (const float4*)(bases + (size_t)kn * 16384);
    for (int idx = tid; idx < 4096; idx += 256) {
        int jrow = idx >> 5, c = idx & 31;
        float4 v = B4[jrow * 32 + c];
        *((float4*)&Blds[jrow * 132 + c * 4]) = v;
    }
    __syncthreads();
    int j1 = q * 32 + (tid >> 3);
    int l = tid & 7;
    float accg[16];
#pragma unroll
    for (int i = 0; i < 16; ++i) accg[i] = 0.f;
    for (int c = 0; c < 32; ++c) {
        float4 b1 = *((const float4*)&Blds[j1 * 132 + c * 4]);
#pragma unroll
        for (int i = 0; i < 16; ++i) {
            float4 b2 = *((const float4*)&Blds[(l + 8 * i) * 132 + c * 4]);
            accg[i] += b1.x * b2.x + b1.y * b2.y + b1.z * b2.z + b1.w * b2.w;
        }
    }
#pragma unroll
    for (int i = 0; i < 16; ++i) {
        int j2 = l + 8 * i;
        ws[WS_G + (((size_t)kn * 32 + (j2 >> 2)) * 128 + j1) * 4 + (j2 & 3)] = accg[i];
    }
    __shared__ __align__(16) float vecl[128];
    __shared__ float vred[2][128];
    int jv = tid & 127, ch = tid >> 7;
    for (int vi = q * 24; vi < q * 24 + 24; ++vi) {
        const float* src; int dstoff;
        if (vi < 16) {
            int tt = vi;
            src = E + (size_t)tokens[tt] * 128;
            dstoff = WS_BX + (tt * 4 + k) * 512 + n * 128;
        } else {
            int r2 = vi - 16; int tt = r2 / 5, s2 = r2 % 5;
            size_t off = (size_t)(((tt * 4 + k) * 5 + s2) * 4 + n) * 128;
            src = noise + off;
            dstoff = WS_BEPS + (int)off;
        }
        if (tid < 32) ((float4*)vecl)[tid] = ((const float4*)src)[tid];
        __syncthreads();
        float a2 = 0.f;
        for (int c = ch * 16; c < ch * 16 + 16; ++c) {
            float4 bv = *((const float4*)&Blds[jv * 132 + c * 4]);
            float4 xv = ((const float4*)vecl)[c];
            a2 += bv.x * xv.x + bv.y * xv.y + bv.z * xv.z + bv.w * xv.w;
        }
        vred[ch][jv] = a2;
        __syncthreads();
        if (tid < 128) ws[dstoff + tid] = vred[0][tid] + vred[1][tid];
        __syncthreads();
    }
}

// ---------------- KAP: 4 blocks x 256 threads; wave n = bubble n; lane owns d=jj, jj+64 ----------------
__global__ __launch_bounds__(256, 1)
void kap(const float* __restrict__ E, const float* __restrict__ noise,
         const int* __restrict__ tokens, const float* __restrict__ bases,
         const float* __restrict__ target_sim, const float* __restrict__ step_size,
         const float* __restrict__ gate_logit, const float* __restrict__ decay_base,
         const float* __restrict__ sensitivity,
         float* __restrict__ ws, int t)
{
    const int k = blockIdx.x;
    const int tid = threadIdx.x;
    const int n = tid >> 6;       // wave index = bubble
    const int jj = tid & 63;
    const int kn = k * 4 + n;
    const int ebuf = t & 1;
    const int d0 = jj, d1 = jj + 64;

    __shared__ float xl[128], ml[128], mmL[128];
    __shared__ __align__(16) float aL[4][128], exL[4][128];
    __shared__ float interL[16];
    __shared__ float wredL[4][8];
    __shared__ float scal[1];

    // G rows d0, d1 (2 x 128 floats = 256 VGPRs; 4 waves/block -> 512 budget, no spill)
    float4 g0[32], g1[32];
    const float4* G4 = (const float4*)(ws + WS_G);
#pragma unroll
    for (int c = 0; c < 32; ++c) {
        g0[c] = G4[((size_t)kn * 32 + c) * 128 + d0];
        g1[c] = G4[((size_t)kn * 32 + c) * 128 + d1];
    }

    // Gram of token t-1 (reads other eq buffer, written by previous kap launch)
    if (t > 0) {
        const float* eqR = ws + WS_EQ2 + (ebuf ^ 1) * 2048;
        int ent = tid >> 2, sub = tid & 3;
        int rr = ent >> 4, cc = ent & 15;
        const float4* ra = (const float4*)(eqR + (4 * k + rr) * 128 + sub * 32);
        const float4* rb = (const float4*)(eqR + cc * 128 + sub * 32);
        float dp = 0.f;
#pragma unroll
        for (int q = 0; q < 8; ++q) {
            float4 a = ra[q], b2 = rb[q];
            dp += a.x * b2.x + a.y * b2.y + a.z * b2.z + a.w * b2.w;
        }
        dp += __shfl_xor(dp, 1); dp += __shfl_xor(dp, 2);
        if (sub == 0) ws[WS_GRAM + (t - 1) * 256 + (4 * k + rr) * 16 + cc] = dp;
    }

    int tok = tokens[t];
    if (tid < 16) interL[tid] = ws[WS_INTER + k * 16 + tid];
    if (tid < 128) { xl[tid] = E[(size_t)tok * 128 + tid]; ml[tid] = ws[WS_MM + k * 128 + tid]; }
    __syncthreads();

    // novelty / decay (wave 0)
    if (n == 0) {
        float x0 = xl[d0], x1 = xl[d1], m0 = ml[d0], m1 = ml[d1];
        float vx = x0*x0 + x1*x1, vm = m0*m0 + m1*m1, vd = x0*m0 + x1*m1;
        for (int m = 32; m; m >>= 1) { vx += __shfl_xor(vx, m); vm += __shfl_xor(vm, m); vd += __shfl_xor(vd, m); }
        if (jj == 0) {
            float xnorm = sqrtf(vx) + EPSF, mnorm = sqrtf(vm) + EPSF;
            float nov = 1.0f - vd / (xnorm * mnorm);
            float novelty = (mnorm > 1e-8f) ? nov : 1.0f;
            scal[0] = 1.0f / (1.0f + expf(-(decay_base[0] - fabsf(sensitivity[0]) * novelty)));
        }
    }
    __syncthreads();
    float dec = scal[0];
    float tgt = target_sim[k];
    float stp = fminf(fmaxf(fabsf(step_size[k]), 0.001f), 0.5f);
    float gate = 1.0f / (1.0f + expf(-gate_logit[k]));

    float e00 = ws[WS_BX + (t*4+k)*512 + n*128 + d0] + dec * ws[WS_BMM + kn*128 + d0];
    float e01 = ws[WS_BX + (t*4+k)*512 + n*128 + d1] + dec * ws[WS_BMM + kn*128 + d1];
    float ex0 = e00, ex1 = e01;
    float a0 = 0.f, a1 = 0.f, be0 = 0.f, be1 = 0.f;
    float u0 = xl[d0] + dec * ml[d0], u1 = xl[d1] + dec * ml[d1];
    exL[n][d0] = ex0; exL[n][d1] = ex1;
    __syncthreads();

    for (int s = 0; s < 5; ++s) {
        float em0[4], em1[4];
#pragma unroll
        for (int m = 0; m < 4; ++m) { em0[m] = exL[m][d0]; em1[m] = exL[m][d1]; }
        float r[7];
#pragma unroll
        for (int m = 0; m < 4; ++m) r[m] = ex0 * em0[m] + ex1 * em1[m];
        r[4] = u0*u0 + u1*u1;
        r[5] = (e00 + be0)*a0 + (e01 + be1)*a1;
        r[6] = a0*(ex0 - e00 - be0) + a1*(ex1 - e01 - be1);
#pragma unroll
        for (int m2 = 32; m2; m2 >>= 1) {
#pragma unroll
            for (int q = 0; q < 7; ++q) r[q] += __shfl_xor(r[q], m2);
        }
        if (jj == 0) {
#pragma unroll
            for (int q = 0; q < 7; ++q) wredL[n][q] = r[q];
        }
        __syncthreads();
        float ssum = 0.f;
#pragma unroll
        for (int m = 0; m < 4; ++m) ssum += sqrtf(fmaxf(wredL[m][4] + 2.f*wredL[m][5] + wredL[m][6], 0.f));
        float cn = gate * (0.25f * ssum + EPSF) * 0.01f;

        float Pnn = wredL[n][n];
        float enn = sqrtf(fmaxf(Pnn, 0.f)) + EPSF;
        float fsh0 = 0.f, fsh1 = 0.f;
#pragma unroll
        for (int m = 0; m < 4; ++m) {
            float Pmm = wredL[m][m];
            float Pnm = wredL[n][m];
            float enm = sqrtf(fmaxf(Pmm, 0.f)) + EPSF;
            float cosnm = Pnm / (enn * enm);
            float fm = (cosnm - tgt) * interL[n * 4 + m];
            float dnn = sqrtf(fmaxf(Pnn - 2.f*Pnm + Pmm, 0.f)) + EPSF;
            float w = fm / dnn;
            fsh0 += w * (ex0 - em0[m]);
            fsh1 += w * (ex1 - em1[m]);
        }
        int nz = (((t*4+k)*5 + s)*4 + n) * 128;
        a0 += stp * fsh0; a1 += stp * fsh1;
        be0 += cn * ws[WS_BEPS + nz + d0]; be1 += cn * ws[WS_BEPS + nz + d1];
        u0 += cn * noise[nz + d0]; u1 += cn * noise[nz + d1];
        aL[n][d0] = a0; aL[n][d1] = a1;
        __syncthreads();
        const float4* a4 = (const float4*)aL[n];
        float y0 = 0.f, y1 = 0.f;
#pragma unroll
        for (int c = 0; c < 32; ++c) {
            float4 av = a4[c];
            y0 += g0[c].x*av.x + g0[c].y*av.y + g0[c].z*av.z + g0[c].w*av.w;
            y1 += g1[c].x*av.x + g1[c].y*av.y + g1[c].z*av.z + g1[c].w*av.w;
        }
        ex0 = e00 + y0 + be0; ex1 = e01 + y1 + be1;
        exL[n][d0] = ex0; exL[n][d1] = ex1;
        __syncthreads();
    }

    // eq finalize: eq[n][d] = u[d] + sum_j B[j][d] * a[n][j]
    {
        const float* Bp = bases + (size_t)kn * 16384;
        float acc0 = 0.f, acc1 = 0.f;
#pragma unroll 8
        for (int j2 = 0; j2 < 128; ++j2) {
            float aj = aL[n][j2];
            acc0 += aj * Bp[j2 * 128 + d0];
            acc1 += aj * Bp[j2 * 128 + d1];
        }
        float eq0 = u0 + acc0, eq1 = u1 + acc1;
        ws[WS_EQ2 + ebuf*2048 + kn*128 + d0] = eq0;
        ws[WS_EQ2 + ebuf*2048 + kn*128 + d1] = eq1;
        unsigned short* eqb = (unsigned short*)(ws + WS_EQBALL);
        {
            int c2 = d0 >> 5, lg = (d0 >> 3) & 3, j8 = d0 & 7;
            eqb[t*2048 + (c2*64 + lg*16 + kn)*8 + j8] = (unsigned short)bfb(eq0);
        }
        {
            int c2 = d1 >> 5, lg = (d1 >> 3) & 3, j8 = d1 & 7;
            eqb[t*2048 + (c2*64 + lg*16 + kn)*8 + j8] = (unsigned short)bfb(eq1);
        }
        exL[n][d0] = eq0; exL[n][d1] = eq1;
        float sq = eq0*eq0 + eq1*eq1;
        for (int m = 32; m; m >>= 1) sq += __shfl_xor(sq, m);
        if (jj == 0) wredL[n][7] = sq;
        __syncthreads();
        if (tid < 4) {
            float ssum4 = wredL[0][7] + wredL[1][7] + wredL[2][7] + wredL[3][7];
            ws[WS_WK + t*16 + 4*k + tid] = 1.0f / (4.0f * (ssum4 + EPSF));
        }
        if (tid < 128) {
            float eqm = 0.25f * (exL[0][tid] + exL[1][tid] + exL[2][tid] + exL[3][tid]);
            float mmn = dec * ml[tid] + (1.f - dec) * eqm;
            ws[WS_MM + k*128 + tid] = mmn;
            mmL[tid] = mmn;
        }
        __syncthreads();
        // bmm rows d0, d1: bmm[kn][j] = B[kn] row j . mm
        const float4* Br0 = (const float4*)(bases + (size_t)kn*16384 + (size_t)d0*128);
        const float4* Br1 = (const float4*)(bases + (size_t)kn*16384 + (size_t)d1*128);
        const float4* mm4 = (const float4*)mmL;
        float b0 = 0.f, b1 = 0.f;
#pragma unroll 8
        for (int c = 0; c < 32; ++c) {
            float4 mv = mm4[c];
            float4 x0 = Br0[c], x1 = Br1[c];
            b0 += x0.x*mv.x + x0.y*mv.y + x0.z*mv.z + x0.w*mv.w;
            b1 += x1.x*mv.x + x1.y*mv.y + x1.z*mv.z + x1.w*mv.w;
        }
        ws[WS_BMM + kn*128 + d0] = b0;
        ws[WS_BMM + kn*128 + d1] = b1;
    }
}

// ---------------- mega: logits GEMM, 4 passes x 4 tokens ----------------
__global__ __launch_bounds__(256, 2)
void mega(const float* __restrict__ E, float* __restrict__ ws, float* __restrict__ out)
{
    int b = blockIdx.x, tid = threadIdx.x;
    int pass = b / 500;
    int bb = b - pass * 500;
    int tok0 = pass * 4;
    int lane = tid & 63, wv = tid >> 6;
    const short8v* eqB = (const short8v*)(ws + WS_EQBALL);
    short8v bfr[4][4];
#pragma unroll
    for (int tk = 0; tk < 4; ++tk)
#pragma unroll
        for (int c2 = 0; c2 < 4; ++c2) bfr[tk][c2] = eqB[(tok0 + tk) * 256 + c2 * 64 + lane];
    float wk[4], zl[4];
#pragma unroll
    for (int tk = 0; tk < 4; ++tk) {
        wk[tk] = ws[WS_WK + (tok0 + tk) * 16 + (lane & 15)];
        zl[tk] = 0.f;
    }
    int tilebase = (bb * 4 + wv) * 64;
#pragma unroll
    for (int it = 0; it < 4; ++it) {
        int rowB = tilebase + it * 16;
        const float* Erow = E + (size_t)(rowB + (lane & 15)) * 128 + ((lane >> 4) * 8);
        float4v acc[4];
#pragma unroll
        for (int tk = 0; tk < 4; ++tk) acc[tk] = (float4v){0.f, 0.f, 0.f, 0.f};
#pragma unroll
        for (int c2 = 0; c2 < 4; ++c2) {
            float4 e0 = *((const float4*)(Erow + c2 * 32));
            float4 e1 = *((const float4*)(Erow + c2 * 32 + 4));
            short8v a;
            a[0] = bfb(e0.x); a[1] = bfb(e0.y); a[2] = bfb(e0.z); a[3] = bfb(e0.w);
            a[4] = bfb(e1.x); a[5] = bfb(e1.y); a[6] = bfb(e1.z); a[7] = bfb(e1.w);
#pragma unroll
            for (int tk = 0; tk < 4; ++tk)
                acc[tk] = __builtin_amdgcn_mfma_f32_16x16x32_bf16(a, bfr[tk][c2], acc[tk], 0, 0, 0);
        }
#pragma unroll
        for (int tk = 0; tk < 4; ++tk) {
            float l0 = wk[tk] * acc[tk][0] * acc[tk][0];
            float l1 = wk[tk] * acc[tk][1] * acc[tk][1];
            float l2 = wk[tk] * acc[tk][2] * acc[tk][2];
            float l3 = wk[tk] * acc[tk][3] * acc[tk][3];
#pragma unroll
            for (int m = 1; m <= 8; m <<= 1) {
                l0 += __shfl_xor(l0, m); l1 += __shfl_xor(l1, m);
                l2 += __shfl_xor(l2, m); l3 += __shfl_xor(l3, m);
            }
            if ((lane & 15) == 0) {
                float4 st; st.x = l0; st.y = l1; st.z = l2; st.w = l3;
                *((float4*)(out + (size_t)(tok0 + tk) * V_ + rowB + (lane >> 4) * 4)) = st;
                zl[tk] += __expf(l0) + __expf(l1) + __expf(l2) + __expf(l3);
            }
        }
    }
#pragma unroll
    for (int tk = 0; tk < 4; ++tk) {
        float z = zl[tk];
        z += __shfl_xor(z, 16); z += __shfl_xor(z, 32);
        if (lane == 0) ws[WS_ZPART + (tok0 + tk) * 2000 + bb * 4 + wv] = z;
    }
}

// ---------------- zk: Z reduce (blk 0-15) + Gram for t=15 (blk 16) ----------------
__global__ __launch_bounds__(256)
void zk(float* __restrict__ ws)
{
    int b = blockIdx.x, tid = threadIdx.x;
    if (b < 16) {
        double s = 0.0;
        for (int i = tid; i < 2000; i += 256) s += (double)ws[WS_ZPART + b * 2000 + i];
        for (int m = 32; m; m >>= 1) s += __shfl_xor(s, m);
        __shared__ double sr[4];
        if ((tid & 63) == 0) sr[tid >> 6] = s;
        __syncthreads();
        if (tid == 0) ws[WS_LNZ + b] = (float)log(sr[0] + sr[1] + sr[2] + sr[3]);
    } else {
        const float* eqR = ws + WS_EQ2 + 2048;   // buffer (15 & 1) == 1
        int aa = tid >> 4, bb = tid & 15;
        const float4* ra = (const float4*)(eqR + aa * 128);
        const float4* rb = (const float4*)(eqR + bb * 128);
        float dp = 0.f;
#pragma unroll 8
        for (int c = 0; c < 32; ++c) {
            float4 a = ra[c], b2 = rb[c];
            dp += a.x * b2.x + a.y * b2.y + a.z * b2.z + a.w * b2.w;
        }
        ws[WS_GRAM + 15 * 256 + tid] = dp;
    }
}

// ---------------- fin1: blk 0-15 single-wave Jacobi (8-lane param precompute); blk 16+ probs ----------------
__global__ __launch_bounds__(256)
void fin1(float* __restrict__ ws, float* __restrict__ out)
{
    int b = blockIdx.x, tid = threadIdx.x;
    if (b < 16) {
        if (tid >= 64) return;
        int tt = b;
        __shared__ float Am[16 * 20];
        __shared__ float cR[16], sR[16];
        int i0 = tid >> 2, j40 = (tid & 3) * 4;
        const float* G = ws + WS_GRAM + tt * 256;
        float wv4[4];
#pragma unroll
        for (int kk = 0; kk < 4; ++kk) {
            float ss = G[(4*kk+0)*17] + G[(4*kk+1)*17] + G[(4*kk+2)*17] + G[(4*kk+3)*17];
            wv4[kk] = 1.0f / (4.0f * (ss + EPSF));
        }
#pragma unroll
        for (int m = 0; m < 4; ++m) {
            int jjv = j40 + m;
            Am[i0 * 20 + jjv] = sqrtf(wv4[i0 >> 2] * wv4[jjv >> 2]) * G[i0 * 16 + jjv];
        }
        // single wave: DS ops wave-ordered, no barriers
        for (int sw = 0; sw < 6; ++sw) {
            for (int r = 0; r < 15; ++r) {
                if (tid < 8) {
                    int p, q;
                    if (tid == 0) { p = 15; q = r % 15; }
                    else { p = (r + tid) % 15; q = (r - tid + 15) % 15; }
                    float c, s;
                    rotfast(Am[p * 20 + p], Am[q * 20 + q], Am[p * 20 + q], c, s);
                    cR[p] = c; sR[p] = -s;
                    cR[q] = c; sR[q] = s;
                }
                int oi; bool ip; jpair(i0, r, oi, ip);
                float ci = cR[i0], siS = sR[i0];
                float nv[4];
#pragma unroll
                for (int m = 0; m < 4; ++m) {
                    int jjv = j40 + m;
                    int oj; bool jp2; jpair(jjv, r, oj, jp2);
                    float cj = cR[jjv], sjS = sR[jjv];
                    float a00 = Am[i0 * 20 + jjv], a01 = Am[i0 * 20 + oj];
                    float a10 = Am[oi * 20 + jjv], a11 = Am[oi * 20 + oj];
                    nv[m] = ci*cj*a00 + ci*sjS*a01 + siS*cj*a10 + siS*sjS*a11;
                }
#pragma unroll
                for (int m = 0; m < 4; ++m) Am[i0 * 20 + j40 + m] = nv[m];
            }
        }
        if (tid == 0) {
            float tot = 112.0f * 1e-12f;
            float lc[16];
            for (int a2 = 0; a2 < 16; ++a2) { lc[a2] = fmaxf(Am[a2 * 20 + a2], 1e-12f); tot += lc[a2]; }
            float S = 0.f;
            for (int a2 = 0; a2 < 16; ++a2) { float pp = lc[a2] / tot; S -= pp * fmaxf(logf(pp), -100.f); }
            float p0 = 1e-12f / tot;
            S -= 112.f * p0 * fmaxf(logf(p0), -100.f);
            out[(size_t)T_ * V_ + tt] = S;
            ws[WS_SRHO + tt] = S;
        }
    } else {
        int b2 = b - 16;
        int tt = b2 / 125, blk = b2 - tt * 125;
        int v = blk * 1024 + tid * 4;
        float lnZ = ws[WS_LNZ + tt];
        float* po = out + (size_t)tt * V_ + v;
        float4 l4 = *((const float4*)po);
        float lp0 = l4.x - lnZ, lp1 = l4.y - lnZ, lp2 = l4.z - lnZ, lp3 = l4.w - lnZ;
        float p0 = __expf(lp0), p1 = __expf(lp1), p2 = __expf(lp2), p3 = __expf(lp3);
        float4 st; st.x = p0; st.y = p1; st.z = p2; st.w = p3;
        *((float4*)po) = st;
        float hp = p0 * fmaxf(lp0, -100.f) + p1 * fmaxf(lp1, -100.f)
                 + p2 * fmaxf(lp2, -100.f) + p3 * fmaxf(lp3, -100.f);
        for (int m = 32; m; m >>= 1) hp += __shfl_xor(hp, m);
        __shared__ float hr[4];
        if ((tid & 63) == 0) hr[tid >> 6] = hp;
        __syncthreads();
        if (tid == 0) ws[WS_HPART + tt * 125 + blk] = hr[0] + hr[1] + hr[2] + hr[3];
    }
}

// ---------------- f2: per-token H reduction ----------------
__global__ __launch_bounds__(128)
void f2_final(float* __restrict__ ws, float* __restrict__ out)
{
    int t = blockIdx.x, tid = threadIdx.x;
    float s = (tid < 125) ? ws[WS_HPART + t * 125 + tid] : 0.f;
    for (int m = 32; m; m >>= 1) s += __shfl_xor(s, m);
    __shared__ float sr[2];
    if ((tid & 63) == 0) sr[tid >> 6] = s;
    __syncthreads();
    if (tid == 0) {
        float H = -(sr[0] + sr[1]);
        float S = ws[WS_SRHO + t];
        out[(size_t)T_ * V_ + T_ + t] = H;
        out[(size_t)T_ * V_ + 2 * T_ + t] = H - S;
    }
}

extern "C" void kernel_launch(void* const* d_in, const int* in_sizes, int n_in,
                              void* d_out, int out_size, void* d_ws, size_t ws_size,
                              hipStream_t stream)
{
    (void)in_sizes; (void)n_in; (void)out_size; (void)ws_size;
    const float* E           = (const float*)d_in[0];
    const float* bases       = (const float*)d_in[1];
    const float* tension     = (const float*)d_in[2];
    const float* temperature = (const float*)d_in[3];
    const float* target_sim  = (const float*)d_in[4];
    const float* step_size   = (const float*)d_in[5];
    const float* gate_logit  = (const float*)d_in[6];
    const float* decay_base  = (const float*)d_in[7];
    const float* sensitivity = (const float*)d_in[8];
    const float* noise       = (const float*)d_in[9];
    const int*   tokens      = (const int*)d_in[10];
    float* out = (float*)d_out;
    float* ws  = (float*)d_ws;

    i2_prep<<<65, 256, 0, stream>>>(bases, E, noise, tokens, tension, temperature, ws);
    for (int t = 0; t < T_; ++t) {
        kap<<<4, 256, 0, stream>>>(E, noise, tokens, bases, target_sim, step_size,
                                   gate_logit, decay_base, sensitivity, ws, t);
    }
    mega<<<2000, 256, 0, stream>>>(E, ws, out);
    zk<<<17, 256, 0, stream>>>(ws);
    fin1<<<16 + T_ * 125, 256, 0, stream>>>(ws, out);
    f2_final<<<T_, 128, 0, stream>>>(ws, out);
}